// Round 3
// baseline (307.059 us; speedup 1.0000x reference)
//
#include <hip/hip_runtime.h>

typedef __attribute__((ext_vector_type(8))) short bf16x8;
typedef __attribute__((ext_vector_type(4))) float f32x4;

#define D_MODEL 1024
#define NHEADS 16
#define HDIM 64
#define SEQ 2048
#define BATCH 2
#define MROWS (BATCH*SEQ)   // 4096
#define NQKV (3*D_MODEL)    // 3072
// softmax in exp2 domain: fold 1/sqrt(64) * log2(e) into Q scale
#define QSCALE 0.1803368801111204f
#define LPAD 72   // LDS row stride in shorts (144B: 16B-aligned)

__device__ __forceinline__ unsigned short f2bf(float f) {
  unsigned int u = __float_as_uint(f);
  u += 0x7FFF + ((u >> 16) & 1);   // RNE
  return (unsigned short)(u >> 16);
}

__device__ __forceinline__ unsigned int pack2bf(float a, float b) {
#if __has_builtin(__builtin_amdgcn_cvt_pk_bf16_f32)
  auto r = __builtin_amdgcn_cvt_pk_bf16_f32(a, b);
  unsigned int u; __builtin_memcpy(&u, &r, 4);
  return u;
#else
  return ((unsigned int)f2bf(b) << 16) | (unsigned int)f2bf(a);
#endif
}

// async global->LDS, 16B per lane (GEMM staging only)
__device__ __forceinline__ void gload16(const void* g, void* l) {
  __builtin_amdgcn_global_load_lds((const __attribute__((address_space(1))) void*)g,
                                   (__attribute__((address_space(3))) void*)l, 16, 0, 0);
}

// fused fp32 -> bf16 conversion for x, Wqkv, Wo (one launch)
#define N4_X     1048576
#define N4_WQKV   786432
#define N4_WO     262144
__global__ void cvt_all_kernel(const float4* __restrict__ x,
                               const float4* __restrict__ wqkv,
                               const float4* __restrict__ wo,
                               ushort4* __restrict__ xb,
                               ushort4* __restrict__ wqkvb,
                               ushort4* __restrict__ wob) {
  int i = blockIdx.x * blockDim.x + threadIdx.x;
  const float4* s; ushort4* d; int j;
  if (i < N4_X)                { s = x;    d = xb;    j = i; }
  else if (i < N4_X + N4_WQKV) { s = wqkv; d = wqkvb; j = i - N4_X; }
  else                         { s = wo;   d = wob;   j = i - (N4_X + N4_WQKV); }
  float4 v = s[j];
  ushort4 o;
  o.x = f2bf(v.x); o.y = f2bf(v.y); o.z = f2bf(v.z); o.w = f2bf(v.w);
  d[j] = o;
}

// C[M,N] = A[M,K](bf16) @ B[N,K]^T(bf16) + bias
// MODE 0: scatter epilogue into Q/K/V bf16 (QKV projection; Q pre-scaled; all [bh][s][e])
// MODE 1: plain fp32 store (output projection)
template<int MODE, int BM>
__global__ __launch_bounds__(256) void gemm_bt_kernel(
    const unsigned short* __restrict__ A,
    const unsigned short* __restrict__ Bm,
    const float* __restrict__ bias,
    float* __restrict__ outF,
    unsigned short* __restrict__ Qb,
    unsigned short* __restrict__ Kb,
    unsigned short* __restrict__ Vb,
    int M, int N, int K)
{
  __shared__ __align__(16) unsigned short As[BM*32];
  __shared__ __align__(16) unsigned short Bs[128*32];
  const int MI = BM / 32;
  const int tid = threadIdx.x;
  const int wave = tid >> 6, lane = tid & 63;
  const int lm = lane & 15, quad = lane >> 4;
  const int wm = (wave >> 1) * (BM/2), wn = (wave & 1) * 64;
  const int m0 = blockIdx.y * BM, n0 = blockIdx.x * 128;

  f32x4 acc[MI][4] = {};

  for (int k0 = 0; k0 < K; k0 += 32) {
    __syncthreads();
#pragma unroll
    for (int i = 0; i < BM/64; i++) {
      int linear = (i * 256 + tid) * 8;          // shorts; lane-contiguous 16B in LDS
      int row = linear >> 5, col = linear & 31;
      gload16(&A[(size_t)(m0 + row) * K + k0 + col], &As[linear]);
    }
#pragma unroll
    for (int i = 0; i < 2; i++) {
      int linear = (i * 256 + tid) * 8;
      int row = linear >> 5, col = linear & 31;
      gload16(&Bm[(size_t)(n0 + row) * K + k0 + col], &Bs[linear]);
    }
    __syncthreads();
    bf16x8 af[MI], bfr[4];
#pragma unroll
    for (int mi = 0; mi < MI; mi++)
      af[mi] = *(const bf16x8*)&As[(wm + mi*16 + lm)*32 + quad*8];
#pragma unroll
    for (int ni = 0; ni < 4; ni++)
      bfr[ni] = *(const bf16x8*)&Bs[(wn + ni*16 + lm)*32 + quad*8];
#pragma unroll
    for (int mi = 0; mi < MI; mi++)
#pragma unroll
      for (int ni = 0; ni < 4; ni++)
        acc[mi][ni] = __builtin_amdgcn_mfma_f32_16x16x32_bf16(af[mi], bfr[ni], acc[mi][ni], 0, 0, 0);
  }

#pragma unroll
  for (int mi = 0; mi < MI; mi++)
#pragma unroll
    for (int ni = 0; ni < 4; ni++)
#pragma unroll
      for (int r = 0; r < 4; r++) {
        int row = m0 + wm + mi*16 + quad*4 + r;   // C/D: row=(lane>>4)*4+reg
        int col = n0 + wn + ni*16 + lm;           //      col=lane&15
        float v = acc[mi][ni][r] + bias[col];
        if (MODE == 1) {
          outF[(size_t)row * N + col] = v;
        } else {
          int b = row >> 11, s = row & (SEQ - 1);
          int h = col / 192;
          int rr = col - h * 192;
          int t = rr >> 6, e = rr & 63;
          int bh = b * NHEADS + h;
          if (t == 0)      Qb[((size_t)bh*SEQ + s)*HDIM + e] = f2bf(v * QSCALE);
          else if (t == 1) Kb[((size_t)bh*SEQ + s)*HDIM + e] = f2bf(v);
          else             Vb[((size_t)bh*SEQ + s)*HDIM + e] = f2bf(v);
        }
      }
}

// V [bh][s][e] -> V^T [bh][e][s], 64x64 tiles via LDS
__global__ __launch_bounds__(256) void vtrans_kernel(
    const unsigned short* __restrict__ Vb, unsigned short* __restrict__ VTb) {
  __shared__ __align__(16) unsigned short T[64*LPAD];
  const int bh = blockIdx.y, s0 = blockIdx.x * 64;
  const int tid = threadIdx.x;
#pragma unroll
  for (int i = 0; i < 2; i++) {
    int ch = i*256 + tid;
    int r = ch >> 3, c = (ch & 7) * 8;    // r = s_local, c = e
    *(uint4*)&T[r*LPAD + c] = *(const uint4*)&Vb[((size_t)bh*SEQ + s0 + r)*HDIM + c];
  }
  __syncthreads();
#pragma unroll
  for (int i = 0; i < 2; i++) {
    int ch = i*256 + tid;
    int e = ch >> 3, c = (ch & 7) * 8;    // e = VT row, c = s_local chunk
    unsigned short tmp[8];
#pragma unroll
    for (int j = 0; j < 8; j++) tmp[j] = T[(c + j)*LPAD + e];
    *(uint4*)&VTb[((size_t)bh*HDIM + e)*SEQ + s0 + c] = *(const uint4*)tmp;
  }
}

// Causal flash attention, S^T orientation, register-double-buffered staging.
// Grid (S/64, B*H); 4 waves; wave owns 16 queries (one per lane column lm).
// Raw s_barrier (lgkmcnt only) so in-flight K/V register preloads are NOT
// drained at barriers -> global latency overlaps a full compute stage.
__global__ __launch_bounds__(256) void flash_attn_kernel(
    const unsigned short* __restrict__ Qb,
    const unsigned short* __restrict__ Kb,
    const unsigned short* __restrict__ VTb,
    unsigned short* __restrict__ Ob)
{
  const int qt = (gridDim.x - 1) - blockIdx.x;   // heavy tiles first
  const int bh = blockIdx.y;
  const int tid = threadIdx.x;
  const int wave = tid >> 6, lane = tid & 63;
  const int lm = lane & 15, quad = lane >> 4;
  const int q0 = qt * 64;
  const int rowq = q0 + wave * 16;
  const int query = rowq + lm;                   // this lane's query row

  __shared__ __align__(16) unsigned short Ks[64*LPAD];     // [key][e]
  __shared__ __align__(16) unsigned short Vs[64*LPAD];     // [e][key] (V^T)
  __shared__ __align__(16) unsigned short Ps[4*16*LPAD];   // per-wave P [query][key]

  const unsigned short* Kbh = Kb  + (size_t)bh*SEQ*HDIM;
  const unsigned short* Vbh = VTb + (size_t)bh*HDIM*SEQ;

  // Q fragment (B-operand [n=query=lm][k=e=quad*8+j]), Q pre-scaled
  bf16x8 qf[2];
#pragma unroll
  for (int kc = 0; kc < 2; kc++)
    qf[kc] = *(const bf16x8*)&Qb[((size_t)bh*SEQ + query)*HDIM + kc*32 + quad*8];

  f32x4 o[4] = {};          // O^T tiles: (e = ei*16+quad*4+r, q = lm)
  float m_run = -1e30f, l_run = 0.f;

  unsigned short* Pw = &Ps[(wave*16 + lm) * LPAD];

  // register staging buffers: 2 K chunks + 2 V chunks of 16B per thread
  uint4 kreg[2], vreg[2];
  const int st_r = tid >> 3;          // 0..31 (with i*256: 0..63)
  const int st_c = (tid & 7) * 8;     // 0..56

  {  // preload kt = 0
#pragma unroll
    for (int i = 0; i < 2; i++) {
      int r = st_r + i*32;
      kreg[i] = *(const uint4*)&Kbh[(size_t)r*HDIM + st_c];
      vreg[i] = *(const uint4*)&Vbh[(size_t)r*SEQ + st_c];
    }
  }

  for (int kt = 0; kt <= qt; ++kt) {
    // write staged regs -> LDS (compiler waits vmcnt for kreg/vreg here)
#pragma unroll
    for (int i = 0; i < 2; i++) {
      int r = st_r + i*32;
      *(uint4*)&Ks[r*LPAD + st_c] = kreg[i];
      *(uint4*)&Vs[r*LPAD + st_c] = vreg[i];
    }
    if (kt < qt) {       // preload next stage; stays in flight across barriers
      const int k0n = (kt + 1) * 64;
#pragma unroll
      for (int i = 0; i < 2; i++) {
        int r = st_r + i*32;
        kreg[i] = *(const uint4*)&Kbh[(size_t)(k0n + r)*HDIM + st_c];
        vreg[i] = *(const uint4*)&Vbh[(size_t)r*SEQ + k0n + st_c];
      }
    }
    asm volatile("s_waitcnt lgkmcnt(0)" ::: "memory");
    __builtin_amdgcn_s_barrier();     // LDS visible; VMEM loads NOT drained

    const int k0 = kt * 64;
    // S^T = K @ Q^T : C tiles (row = key-in-tile, col = query)
    f32x4 sc[4] = {};
#pragma unroll
    for (int kc = 0; kc < 2; kc++)
#pragma unroll
      for (int mi = 0; mi < 4; mi++) {
        bf16x8 kf = *(const bf16x8*)&Ks[(mi*16 + lm)*LPAD + kc*32 + quad*8];
        sc[mi] = __builtin_amdgcn_mfma_f32_16x16x32_bf16(kf, qf[kc], sc[mi], 0, 0, 0);
      }

    if (k0 + 63 > rowq) {    // causal mask needed (wave-uniform branch)
#pragma unroll
      for (int mi = 0; mi < 4; mi++)
#pragma unroll
        for (int r = 0; r < 4; r++) {
          int key = k0 + mi*16 + quad*4 + r;
          if (key > query) sc[mi][r] = -1e30f;
        }
    }

    // online softmax (exp2 domain): 16 in-lane values belong to query `lm`
    float mx = sc[0][0];
#pragma unroll
    for (int mi = 0; mi < 4; mi++)
#pragma unroll
      for (int r = 0; r < 4; r++) mx = fmaxf(mx, sc[mi][r]);
    mx = fmaxf(mx, __shfl_xor(mx, 16, 64));
    mx = fmaxf(mx, __shfl_xor(mx, 32, 64));
    float mnew = fmaxf(m_run, mx);
    float alpha = exp2f(m_run - mnew);
    float p[4][4];
    float rs = 0.f;
#pragma unroll
    for (int mi = 0; mi < 4; mi++)
#pragma unroll
      for (int r = 0; r < 4; r++) {
        p[mi][r] = exp2f(sc[mi][r] - mnew);
        rs += p[mi][r];
      }
    rs += __shfl_xor(rs, 16, 64);
    rs += __shfl_xor(rs, 32, 64);
    l_run = l_run * alpha + rs;
    m_run = mnew;
#pragma unroll
    for (int ei = 0; ei < 4; ei++)
#pragma unroll
      for (int r = 0; r < 4; r++) o[ei][r] *= alpha;

    // P^T -> LDS as P[query][key], one b64 write per mi (conflict-light)
#pragma unroll
    for (int mi = 0; mi < 4; mi++) {
      uint2 u;
      u.x = pack2bf(p[mi][0], p[mi][1]);
      u.y = pack2bf(p[mi][2], p[mi][3]);
      *(uint2*)&Pw[mi*16 + quad*4] = u;
    }
    asm volatile("s_waitcnt lgkmcnt(0)" ::: "memory");  // same-wave write->read

    // O^T += V^T @ P^T : A = V^T[e][key], B = P[q][key]
#pragma unroll
    for (int kc = 0; kc < 2; kc++) {
      bf16x8 pf = *(const bf16x8*)&Pw[kc*32 + quad*8];
#pragma unroll
      for (int ei = 0; ei < 4; ei++) {
        bf16x8 vf = *(const bf16x8*)&Vs[(ei*16 + lm)*LPAD + kc*32 + quad*8];
        o[ei] = __builtin_amdgcn_mfma_f32_16x16x32_bf16(vf, pf, o[ei], 0, 0, 0);
      }
    }

    asm volatile("s_waitcnt lgkmcnt(0)" ::: "memory");
    __builtin_amdgcn_s_barrier();     // all waves done reading Ks/Vs
  }

  // epilogue: O^T/l -> Ob[bh][s][e] (bf16), 8B packed stores
  float inv = 1.0f / l_run;
  size_t obase = ((size_t)bh*SEQ + query) * HDIM;
#pragma unroll
  for (int ei = 0; ei < 4; ei++) {
    uint2 u;
    u.x = pack2bf(o[ei][0]*inv, o[ei][1]*inv);
    u.y = pack2bf(o[ei][2]*inv, o[ei][3]*inv);
    *(uint2*)&Ob[obase + ei*16 + quad*4] = u;
  }
}

extern "C" void kernel_launch(void* const* d_in, const int* in_sizes, int n_in,
                              void* d_out, int out_size, void* d_ws, size_t ws_size,
                              hipStream_t stream) {
  const float* x    = (const float*)d_in[0];
  const float* Wqkv = (const float*)d_in[1];
  const float* bqkv = (const float*)d_in[2];
  const float* Wo   = (const float*)d_in[3];
  const float* bo   = (const float*)d_in[4];
  float* out = (float*)d_out;

  char* ws = (char*)d_ws;
  unsigned short* Xbf    = (unsigned short*)(ws);              // 8 MiB (reused as VTb)
  unsigned short* Wqkvbf = (unsigned short*)(ws + 8388608);    // 6 MiB
  unsigned short* Wobf   = (unsigned short*)(ws + 14680064);   // 2 MiB
  unsigned short* Qb     = (unsigned short*)(ws + 16777216);   // 8 MiB [B,H,S,hd]
  unsigned short* Kb     = (unsigned short*)(ws + 25165824);   // 8 MiB [B,H,S,hd]
  unsigned short* Vb     = (unsigned short*)(ws + 33554432);   // 8 MiB [B,H,S,hd]
  unsigned short* Ob     = (unsigned short*)(ws + 41943040);   // 8 MiB [B,H,S,hd]
  unsigned short* VTb    = Xbf;   // Xbf dead after GEMM1 (stream-ordered)

  cvt_all_kernel<<<8192, 256, 0, stream>>>(
      (const float4*)x, (const float4*)Wqkv, (const float4*)Wo,
      (ushort4*)Xbf, (ushort4*)Wqkvbf, (ushort4*)Wobf);

  gemm_bt_kernel<0,128><<<dim3(24, 32), 256, 0, stream>>>(
      Xbf, Wqkvbf, bqkv, nullptr, Qb, Kb, Vb, MROWS, NQKV, D_MODEL);

  vtrans_kernel<<<dim3(32, 32), 256, 0, stream>>>(Vb, VTb);

  flash_attn_kernel<<<dim3(32, 32), 256, 0, stream>>>(Qb, Kb, VTb, Ob);

  gemm_bt_kernel<1,64><<<dim3(8, 64), 256, 0, stream>>>(
      Ob, Wobf, bo, out, nullptr, nullptr, nullptr, MROWS, D_MODEL, D_MODEL);
}

// Round 4
// 272.361 us; speedup vs baseline: 1.1274x; 1.1274x over previous
//
#include <hip/hip_runtime.h>

typedef __attribute__((ext_vector_type(8))) short bf16x8;
typedef __attribute__((ext_vector_type(4))) float f32x4;

#define D_MODEL 1024
#define NHEADS 16
#define HDIM 64
#define SEQ 2048
#define BATCH 2
#define MROWS (BATCH*SEQ)   // 4096
#define NQKV (3*D_MODEL)    // 3072
// softmax in exp2 domain: fold 1/sqrt(64) * log2(e) into Q scale
#define QSCALE 0.1803368801111204f
#define LPAD 72   // LDS row stride in shorts for vtrans (144B)

__device__ __forceinline__ unsigned short f2bf(float f) {
  unsigned int u = __float_as_uint(f);
  u += 0x7FFF + ((u >> 16) & 1);   // RNE
  return (unsigned short)(u >> 16);
}

__device__ __forceinline__ unsigned int pack2bf(float a, float b) {
#if __has_builtin(__builtin_amdgcn_cvt_pk_bf16_f32)
  auto r = __builtin_amdgcn_cvt_pk_bf16_f32(a, b);
  unsigned int u; __builtin_memcpy(&u, &r, 4);
  return u;
#else
  return ((unsigned int)f2bf(b) << 16) | (unsigned int)f2bf(a);
#endif
}

// async global->LDS, 16B per lane (GEMM staging only)
__device__ __forceinline__ void gload16(const void* g, void* l) {
  __builtin_amdgcn_global_load_lds((const __attribute__((address_space(1))) void*)g,
                                   (__attribute__((address_space(3))) void*)l, 16, 0, 0);
}

// fused fp32 -> bf16 conversion for x, Wqkv, Wo (one launch)
#define N4_X     1048576
#define N4_WQKV   786432
#define N4_WO     262144
__global__ void cvt_all_kernel(const float4* __restrict__ x,
                               const float4* __restrict__ wqkv,
                               const float4* __restrict__ wo,
                               ushort4* __restrict__ xb,
                               ushort4* __restrict__ wqkvb,
                               ushort4* __restrict__ wob) {
  int i = blockIdx.x * blockDim.x + threadIdx.x;
  const float4* s; ushort4* d; int j;
  if (i < N4_X)                { s = x;    d = xb;    j = i; }
  else if (i < N4_X + N4_WQKV) { s = wqkv; d = wqkvb; j = i - N4_X; }
  else                         { s = wo;   d = wob;   j = i - (N4_X + N4_WQKV); }
  float4 v = s[j];
  ushort4 o;
  o.x = f2bf(v.x); o.y = f2bf(v.y); o.z = f2bf(v.z); o.w = f2bf(v.w);
  d[j] = o;
}

// C[M,N] = A[M,K](bf16) @ B[N,K]^T(bf16) + bias
// MODE 0: scatter epilogue into Q/K/V bf16 (QKV projection; Q pre-scaled; all [bh][s][e])
// MODE 1: plain fp32 store (output projection)
template<int MODE, int BM>
__global__ __launch_bounds__(256) void gemm_bt_kernel(
    const unsigned short* __restrict__ A,
    const unsigned short* __restrict__ Bm,
    const float* __restrict__ bias,
    float* __restrict__ outF,
    unsigned short* __restrict__ Qb,
    unsigned short* __restrict__ Kb,
    unsigned short* __restrict__ Vb,
    int M, int N, int K)
{
  __shared__ __align__(16) unsigned short As[BM*32];
  __shared__ __align__(16) unsigned short Bs[128*32];
  const int MI = BM / 32;
  const int tid = threadIdx.x;
  const int wave = tid >> 6, lane = tid & 63;
  const int lm = lane & 15, quad = lane >> 4;
  const int wm = (wave >> 1) * (BM/2), wn = (wave & 1) * 64;
  const int m0 = blockIdx.y * BM, n0 = blockIdx.x * 128;

  f32x4 acc[MI][4] = {};

  for (int k0 = 0; k0 < K; k0 += 32) {
    __syncthreads();
#pragma unroll
    for (int i = 0; i < BM/64; i++) {
      int linear = (i * 256 + tid) * 8;          // shorts; lane-contiguous 16B in LDS
      int row = linear >> 5, col = linear & 31;
      gload16(&A[(size_t)(m0 + row) * K + k0 + col], &As[linear]);
    }
#pragma unroll
    for (int i = 0; i < 2; i++) {
      int linear = (i * 256 + tid) * 8;
      int row = linear >> 5, col = linear & 31;
      gload16(&Bm[(size_t)(n0 + row) * K + k0 + col], &Bs[linear]);
    }
    __syncthreads();
    bf16x8 af[MI], bfr[4];
#pragma unroll
    for (int mi = 0; mi < MI; mi++)
      af[mi] = *(const bf16x8*)&As[(wm + mi*16 + lm)*32 + quad*8];
#pragma unroll
    for (int ni = 0; ni < 4; ni++)
      bfr[ni] = *(const bf16x8*)&Bs[(wn + ni*16 + lm)*32 + quad*8];
#pragma unroll
    for (int mi = 0; mi < MI; mi++)
#pragma unroll
      for (int ni = 0; ni < 4; ni++)
        acc[mi][ni] = __builtin_amdgcn_mfma_f32_16x16x32_bf16(af[mi], bfr[ni], acc[mi][ni], 0, 0, 0);
  }

#pragma unroll
  for (int mi = 0; mi < MI; mi++)
#pragma unroll
    for (int ni = 0; ni < 4; ni++)
#pragma unroll
      for (int r = 0; r < 4; r++) {
        int row = m0 + wm + mi*16 + quad*4 + r;   // C/D: row=(lane>>4)*4+reg
        int col = n0 + wn + ni*16 + lm;           //      col=lane&15
        float v = acc[mi][ni][r] + bias[col];
        if (MODE == 1) {
          outF[(size_t)row * N + col] = v;
        } else {
          int b = row >> 11, s = row & (SEQ - 1);
          int h = col / 192;
          int rr = col - h * 192;
          int t = rr >> 6, e = rr & 63;
          int bh = b * NHEADS + h;
          if (t == 0)      Qb[((size_t)bh*SEQ + s)*HDIM + e] = f2bf(v * QSCALE);
          else if (t == 1) Kb[((size_t)bh*SEQ + s)*HDIM + e] = f2bf(v);
          else             Vb[((size_t)bh*SEQ + s)*HDIM + e] = f2bf(v);
        }
      }
}

// V [bh][s][e] -> V^T [bh][e][s], 64x64 tiles via LDS
__global__ __launch_bounds__(256) void vtrans_kernel(
    const unsigned short* __restrict__ Vb, unsigned short* __restrict__ VTb) {
  __shared__ __align__(16) unsigned short T[64*LPAD];
  const int bh = blockIdx.y, s0 = blockIdx.x * 64;
  const int tid = threadIdx.x;
#pragma unroll
  for (int i = 0; i < 2; i++) {
    int ch = i*256 + tid;
    int r = ch >> 3, c = (ch & 7) * 8;    // r = s_local, c = e
    *(uint4*)&T[r*LPAD + c] = *(const uint4*)&Vb[((size_t)bh*SEQ + s0 + r)*HDIM + c];
  }
  __syncthreads();
#pragma unroll
  for (int i = 0; i < 2; i++) {
    int ch = i*256 + tid;
    int e = ch >> 3, c = (ch & 7) * 8;    // e = VT row, c = s_local chunk
    unsigned short tmp[8];
#pragma unroll
    for (int j = 0; j < 8; j++) tmp[j] = T[(c + j)*LPAD + e];
    *(uint4*)&VTb[((size_t)bh*HDIM + e)*SEQ + s0 + c] = *(const uint4*)tmp;
  }
}

// Causal flash attention, wave-autonomous (NO __syncthreads).
// Grid (16, B*H), 4 waves/block; wave widx = blockIdx.x*4+wave handles q-tiles
// {127-widx, widx} (16 queries each; paired so every wave does ~33 stages).
// K and V^T MFMA A-fragments load DIRECTLY from global (16B/lane contiguous);
// only the wave-private P round-trip touches LDS (XOR-swizzled, conflict-free).
__global__ __launch_bounds__(256) void flash_attn_kernel(
    const unsigned short* __restrict__ Qb,
    const unsigned short* __restrict__ Kb,
    const unsigned short* __restrict__ VTb,
    unsigned short* __restrict__ Ob)
{
  const int bh = blockIdx.y;
  const int tid = threadIdx.x;
  const int wave = tid >> 6, lane = tid & 63;
  const int lm = lane & 15, quad = lane >> 4;
  const int widx = blockIdx.x * 4 + wave;   // 0..63

  __shared__ __align__(16) unsigned short Ps[4][16*64];  // per-wave P, swizzled

  const unsigned short* Qbh  = Qb  + (size_t)bh*SEQ*HDIM;
  const unsigned short* Kbh  = Kb  + (size_t)bh*SEQ*HDIM;
  const unsigned short* VTbh = VTb + (size_t)bh*HDIM*SEQ;
  unsigned short* Pw = &Ps[wave][lm * 64];   // this lane's P row (query=lm)
  const int sw = lm & 7;                     // 16B-chunk XOR swizzle

  for (int rep = 0; rep < 2; rep++) {
    const int t = rep ? widx : (127 - widx); // q-tile index (16 queries)
    const int query = t * 16 + lm;

    bf16x8 qf[2];
#pragma unroll
    for (int kc = 0; kc < 2; kc++)
      qf[kc] = *(const bf16x8*)&Qbh[(size_t)query*HDIM + kc*32 + quad*8];

    f32x4 o[4] = {};
    float m_run = -1e30f, l_run = 0.f;
    const int nkt = (t >> 2) + 1;

    for (int kt = 0; kt < nkt; ++kt) {
      const int k0 = kt * 64;
      // direct global A-fragment loads (16B/lane, contiguous)
      bf16x8 kfr[4][2], vfr[4][2];
#pragma unroll
      for (int mi = 0; mi < 4; mi++)
#pragma unroll
        for (int kc = 0; kc < 2; kc++)
          kfr[mi][kc] = *(const bf16x8*)&Kbh[(size_t)(k0 + mi*16 + lm)*HDIM + kc*32 + quad*8];
#pragma unroll
      for (int ei = 0; ei < 4; ei++)
#pragma unroll
        for (int kc = 0; kc < 2; kc++)
          vfr[ei][kc] = *(const bf16x8*)&VTbh[(size_t)(ei*16 + lm)*SEQ + k0 + kc*32 + quad*8];

      // S^T = K @ Q^T : C rows = keys, cols = queries
      f32x4 sc[4] = {};
#pragma unroll
      for (int kc = 0; kc < 2; kc++)
#pragma unroll
        for (int mi = 0; mi < 4; mi++)
          sc[mi] = __builtin_amdgcn_mfma_f32_16x16x32_bf16(kfr[mi][kc], qf[kc], sc[mi], 0, 0, 0);

      if (kt == nkt - 1) {   // causal mask (wave-uniform branch)
#pragma unroll
        for (int mi = 0; mi < 4; mi++)
#pragma unroll
          for (int r = 0; r < 4; r++) {
            int key = k0 + mi*16 + quad*4 + r;
            if (key > query) sc[mi][r] = -1e30f;
          }
      }

      // online softmax (exp2 domain); lane's 16 values all belong to query lm
      float mx = sc[0][0];
#pragma unroll
      for (int mi = 0; mi < 4; mi++)
#pragma unroll
        for (int r = 0; r < 4; r++) mx = fmaxf(mx, sc[mi][r]);
      mx = fmaxf(mx, __shfl_xor(mx, 16, 64));
      mx = fmaxf(mx, __shfl_xor(mx, 32, 64));
      float mnew = fmaxf(m_run, mx);
      float alpha = exp2f(m_run - mnew);
      float p[4][4];
      float rs = 0.f;
#pragma unroll
      for (int mi = 0; mi < 4; mi++)
#pragma unroll
        for (int r = 0; r < 4; r++) {
          p[mi][r] = exp2f(sc[mi][r] - mnew);
          rs += p[mi][r];
        }
      rs += __shfl_xor(rs, 16, 64);
      rs += __shfl_xor(rs, 32, 64);
      l_run = l_run * alpha + rs;
      m_run = mnew;
#pragma unroll
      for (int ei = 0; ei < 4; ei++)
#pragma unroll
        for (int r = 0; r < 4; r++) o[ei][r] *= alpha;

      // P -> wave-private LDS, swizzled b64 writes (2-way max = free)
#pragma unroll
      for (int mi = 0; mi < 4; mi++) {
        uint2 u;
        u.x = pack2bf(p[mi][0], p[mi][1]);
        u.y = pack2bf(p[mi][2], p[mi][3]);
        int chunk = (2*mi + (quad >> 1)) ^ sw;
        *(uint2*)&Pw[chunk*8 + (quad & 1)*4] = u;
      }
      asm volatile("s_waitcnt lgkmcnt(0)" ::: "memory");  // same-wave cross-lane

      // O^T += V^T @ P^T : A = V^T frags (regs), B = P from LDS (swizzled b128)
#pragma unroll
      for (int kc = 0; kc < 2; kc++) {
        bf16x8 pf = *(const bf16x8*)&Pw[((kc*4 + quad) ^ sw) * 8];
#pragma unroll
        for (int ei = 0; ei < 4; ei++)
          o[ei] = __builtin_amdgcn_mfma_f32_16x16x32_bf16(vfr[ei][kc], pf, o[ei], 0, 0, 0);
      }
    }

    // epilogue: O^T/l -> Ob[bh][s][e] (bf16), 8B packed stores
    float inv = 1.0f / l_run;
    size_t obase = ((size_t)bh*SEQ + query) * HDIM;
#pragma unroll
    for (int ei = 0; ei < 4; ei++) {
      uint2 u;
      u.x = pack2bf(o[ei][0]*inv, o[ei][1]*inv);
      u.y = pack2bf(o[ei][2]*inv, o[ei][3]*inv);
      *(uint2*)&Ob[obase + ei*16 + quad*4] = u;
    }
  }
}

extern "C" void kernel_launch(void* const* d_in, const int* in_sizes, int n_in,
                              void* d_out, int out_size, void* d_ws, size_t ws_size,
                              hipStream_t stream) {
  const float* x    = (const float*)d_in[0];
  const float* Wqkv = (const float*)d_in[1];
  const float* bqkv = (const float*)d_in[2];
  const float* Wo   = (const float*)d_in[3];
  const float* bo   = (const float*)d_in[4];
  float* out = (float*)d_out;

  char* ws = (char*)d_ws;
  unsigned short* Xbf    = (unsigned short*)(ws);              // 8 MiB (reused as VTb)
  unsigned short* Wqkvbf = (unsigned short*)(ws + 8388608);    // 6 MiB
  unsigned short* Wobf   = (unsigned short*)(ws + 14680064);   // 2 MiB
  unsigned short* Qb     = (unsigned short*)(ws + 16777216);   // 8 MiB [B,H,S,hd]
  unsigned short* Kb     = (unsigned short*)(ws + 25165824);   // 8 MiB [B,H,S,hd]
  unsigned short* Vb     = (unsigned short*)(ws + 33554432);   // 8 MiB [B,H,S,hd]
  unsigned short* Ob     = (unsigned short*)(ws + 41943040);   // 8 MiB [B,H,S,hd]
  unsigned short* VTb    = Xbf;   // Xbf dead after GEMM1 (stream-ordered)

  cvt_all_kernel<<<8192, 256, 0, stream>>>(
      (const float4*)x, (const float4*)Wqkv, (const float4*)Wo,
      (ushort4*)Xbf, (ushort4*)Wqkvbf, (ushort4*)Wobf);

  gemm_bt_kernel<0,128><<<dim3(24, 32), 256, 0, stream>>>(
      Xbf, Wqkvbf, bqkv, nullptr, Qb, Kb, Vb, MROWS, NQKV, D_MODEL);

  vtrans_kernel<<<dim3(32, 32), 256, 0, stream>>>(Vb, VTb);

  flash_attn_kernel<<<dim3(16, 32), 256, 0, stream>>>(Qb, Kb, VTb, Ob);

  gemm_bt_kernel<1,64><<<dim3(8, 64), 256, 0, stream>>>(
      Ob, Wobf, bo, out, nullptr, nullptr, nullptr, MROWS, D_MODEL, D_MODEL);
}